// Round 5
// baseline (195.882 us; speedup 1.0000x reference)
//
#include <hip/hip_runtime.h>
#include <hip/hip_bf16.h>

#define NE    16
#define KDIM  1024
#define NDIM  1024
#define BATCH 8192
#define TM    128
#define TN    64
#define MAXT  96          // max live m-tiles = 64 + 15 = 79, padded

typedef __attribute__((ext_vector_type(8))) short short8;
typedef __attribute__((ext_vector_type(4))) float floatx4;
typedef unsigned short ushort_t;

// ---- ws layout (bytes) ----
#define O_CNT  0
#define O_TG0  256
#define O_TE   1024
#define O_TEND 2048
#define O_POS  4096                     // int[8192]
#define O_TOK  36864                    // int[8320]
#define O_PA   73728                    // ushort[(8192+128)*1024]
#define O_W    17113088                 // ushort[16*1024*1024]
#define WS_REQ 50667520

#define GLOAD_LDS(gp, lp) __builtin_amdgcn_global_load_lds( \
    (const __attribute__((address_space(1))) unsigned int*)(gp), \
    (__attribute__((address_space(3))) unsigned int*)(lp), 16, 0, 0)

__device__ __forceinline__ unsigned int pk2bf(float x, float y) {
    __hip_bfloat162 h = __float22bfloat162_rn(make_float2(x, y));
    unsigned int u;
    __builtin_memcpy(&u, &h, 4);
    return u;
}

// ---------------- fast path ----------------

__global__ void zero_k(int* cnt) {
    if (threadIdx.x < NE) cnt[threadIdx.x] = 0;
}

__global__ void hist_k(const int* __restrict__ gate, int* cnt, int* pos) {
    int t = blockIdx.x * blockDim.x + threadIdx.x;
    if (t < BATCH) pos[t] = atomicAdd(&cnt[gate[t]], 1);
}

// deep-MLP prep: token gather (4 rows/block), weight cvt (8 float4/thread),
// tile-map build in last block
__global__ __launch_bounds__(256) void prep_k(
        const float* __restrict__ inp, const float* __restrict__ wgt,
        const int* __restrict__ gate, const int* __restrict__ pos,
        const int* __restrict__ cnt, ushort_t* __restrict__ pA,
        ushort_t* __restrict__ pW, int* __restrict__ tok,
        int* __restrict__ tg0, int* __restrict__ te, int* __restrict__ tend) {
    __shared__ int ntot;
    const int b = blockIdx.x, tid = threadIdx.x;
    if (b < BATCH / 4) {
        // 4 token rows per block; 256 threads = 2 rows per pass, 8 floats/thread
        const int col = (tid & 127) * 8;
        int g[2]; float4 v0[2], v1[2];
        #pragma unroll
        for (int p = 0; p < 2; ++p) {
            int j = p * 2 + (tid >> 7);
            int t = b * 4 + j;
            int e = gate[t];
            int off = 0;
            #pragma unroll
            for (int k = 0; k < NE; ++k) off += (k < e) ? cnt[k] : 0;
            g[p] = off + pos[t];
            v0[p] = *(const float4*)&inp[(size_t)t * KDIM + col];
            v1[p] = *(const float4*)&inp[(size_t)t * KDIM + col + 4];
        }
        #pragma unroll
        for (int p = 0; p < 2; ++p) {
            uint4 u = make_uint4(pk2bf(v0[p].x, v0[p].y), pk2bf(v0[p].z, v0[p].w),
                                 pk2bf(v1[p].x, v1[p].y), pk2bf(v1[p].z, v1[p].w));
            *(uint4*)&pA[(size_t)g[p] * KDIM + col] = u;
            if (col == 0) tok[g[p]] = b * 4 + p * 2 + (tid >> 7);
        }
    } else if (b < BATCH / 4 + 2048) {
        // weight cvt: 8192 floats per block, 8 independent float4 loads/thread
        size_t base = (size_t)(b - BATCH / 4) * 8192 + tid * 8;
        float4 va[4], vb[4];
        #pragma unroll
        for (int i = 0; i < 4; ++i) {
            va[i] = *(const float4*)&wgt[base + i * 2048];
            vb[i] = *(const float4*)&wgt[base + i * 2048 + 4];
        }
        #pragma unroll
        for (int i = 0; i < 4; ++i) {
            uint4 u = make_uint4(pk2bf(va[i].x, va[i].y), pk2bf(va[i].z, va[i].w),
                                 pk2bf(vb[i].x, vb[i].y), pk2bf(vb[i].z, vb[i].w));
            *(uint4*)&pW[base + i * 2048] = u;
        }
    } else {
        if (tid < NE) {
            int o = 0, ts = 0;
            for (int j = 0; j < NE; ++j) {
                int c = cnt[j];
                if (j < tid) { o += c; ts += (c + TM - 1) / TM; }
            }
            int c = cnt[tid];
            if (tid == NE - 1) ntot = ts + (c + TM - 1) / TM;
            int nt = ts;
            for (int r = 0; r < c; r += TM) {
                int r0 = (r + TM <= c) ? r : (c > TM ? c - TM : 0);
                tg0[nt] = o + r0; te[nt] = tid; tend[nt] = o + c; ++nt;
            }
        }
        __syncthreads();
        for (int i = ntot + tid; i < MAXT; i += 256) {
            tg0[i] = 0; te[i] = 0; tend[i] = 0;
        }
    }
}

// single-buffer BK=64, m97-style 2-barrier, XOR-swizzled LDS chunks
__global__ __launch_bounds__(256, 5) void moe_gemm4_k(
        const ushort_t* __restrict__ pA, const ushort_t* __restrict__ pW,
        const int* __restrict__ tg0, const int* __restrict__ teArr,
        const int* __restrict__ tend, const int* __restrict__ tok,
        float* __restrict__ out) {
    const int y   = blockIdx.y;
    const int g0  = tg0[y];
    const int end = tend[y];
    if (g0 >= end) return;
    const int e    = teArr[y];
    const int out0 = blockIdx.x * TN;

    __shared__ ushort_t As[TM][64];   // 16 KB, chunk-swizzled
    __shared__ ushort_t Bs[TN][64];   //  8 KB
    __shared__ int tok_s[TM];

    const int tid = threadIdx.x;
    if (tid < TM) tok_s[tid] = tok[g0 + tid];

    const int wave = tid >> 6, lane = tid & 63;
    const int wm = (wave >> 1) * 64;
    const int wn = (wave & 1) * 32;
    const int quad = lane >> 4, l16 = lane & 15;

    const ushort_t* Ab = pA + (size_t)g0 * KDIM;
    const ushort_t* Bb = pW + (size_t)e * (KDIM * NDIM) + (size_t)out0 * KDIM;

    floatx4 acc[4][2] = {};
    const int slotw = wave * 64 + lane;

    for (int k0 = 0; k0 < KDIM; k0 += 64) {
        #pragma unroll
        for (int i = 0; i < 4; ++i) {
            int slot = i * 256 + slotw;
            int row = slot >> 3;
            int kc = (slot & 7) ^ (row & 7);
            GLOAD_LDS(Ab + (size_t)row * KDIM + k0 + kc * 8,
                      (ushort_t*)As + (size_t)(i * 256 + wave * 64) * 8);
        }
        #pragma unroll
        for (int i = 0; i < 2; ++i) {
            int slot = i * 256 + slotw;
            int row = slot >> 3;
            int kc = (slot & 7) ^ (row & 7);
            GLOAD_LDS(Bb + (size_t)row * KDIM + k0 + kc * 8,
                      (ushort_t*)Bs + (size_t)(i * 256 + wave * 64) * 8);
        }
        __syncthreads();                 // drain DMA -> LDS ready
        #pragma unroll
        for (int s = 0; s < 2; ++s) {
            short8 a[4], b[2];
            #pragma unroll
            for (int i = 0; i < 4; ++i) {
                int r = wm + i * 16 + l16;
                a[i] = *(const short8*)&As[r][((s * 4 + quad) ^ (r & 7)) * 8];
            }
            #pragma unroll
            for (int j = 0; j < 2; ++j) {
                int r = wn + j * 16 + l16;
                b[j] = *(const short8*)&Bs[r][((s * 4 + quad) ^ (r & 7)) * 8];
            }
            #pragma unroll
            for (int mi = 0; mi < 4; ++mi)
                #pragma unroll
                for (int nj = 0; nj < 2; ++nj)
                    acc[mi][nj] = __builtin_amdgcn_mfma_f32_16x16x32_bf16(
                        a[mi], b[nj], acc[mi][nj], 0, 0, 0);
        }
        __syncthreads();                 // protect LDS before next stage
    }

    // C/D layout: col=lane&15, row=quad*4+reg (verified m89/m91)
    #pragma unroll
    for (int mi = 0; mi < 4; ++mi) {
        #pragma unroll
        for (int r = 0; r < 4; ++r) {
            int lrow = wm + mi * 16 + quad * 4 + r;
            if (g0 + lrow < end) {
                int t = tok_s[lrow];
                float* orow = out + (size_t)t * NDIM + out0 + wn + l16;
                #pragma unroll
                for (int nj = 0; nj < 2; ++nj)
                    orow[nj * 16] = acc[mi][nj][r];
            }
        }
    }
}

// ---------------- fallback path (round-1, known-passing) ----------------
#define LDW 20
__global__ void bin_tokens_k(const int* __restrict__ gate, int* cnt, int* idx) {
    int t = blockIdx.x * blockDim.x + threadIdx.x;
    if (t < BATCH) {
        int e = gate[t];
        int p = atomicAdd(&cnt[e], 1);
        idx[e * BATCH + p] = t;
    }
}

__global__ __launch_bounds__(256) void moe_gemm_k(
        const float* __restrict__ inp, const float* __restrict__ wgt,
        const int* __restrict__ cnt, const int* __restrict__ idx,
        float* __restrict__ out) {
    const int e = blockIdx.z;
    const int n_e = cnt[e];
    const int row0 = blockIdx.y * TM;
    if (row0 >= n_e) return;
    const int out0 = blockIdx.x * 128;
    __shared__ unsigned int As[TM * LDW];
    __shared__ unsigned int Bs[TM * LDW];
    __shared__ int tok_s[TM];
    const int tid = threadIdx.x;
    if (tid < TM) {
        int g = row0 + tid;
        tok_s[tid] = (g < n_e) ? idx[e * BATCH + g] : -1;
    }
    const int wave = tid >> 6, lane = tid & 63;
    const int wm = (wave >> 1) * 64, wn = (wave & 1) * 64;
    const int quad = lane >> 4, l16 = lane & 15;
    floatx4 acc[4][4] = {};
    const int cg = (tid & 7) * 4;
    const int rbase = tid >> 3;
    const float* wbase = wgt + (size_t)e * KDIM * NDIM;
    for (int k0 = 0; k0 < KDIM; k0 += 32) {
        __syncthreads();
        #pragma unroll
        for (int p = 0; p < 4; ++p) {
            int row = p * 32 + rbase;
            int t = tok_s[row];
            float4 va = make_float4(0.f, 0.f, 0.f, 0.f);
            if (t >= 0) va = *(const float4*)&inp[(size_t)t * KDIM + k0 + cg];
            As[row * LDW + (cg >> 1)]     = pk2bf(va.x, va.y);
            As[row * LDW + (cg >> 1) + 1] = pk2bf(va.z, va.w);
            float4 vb = *(const float4*)&wbase[(size_t)(out0 + row) * KDIM + k0 + cg];
            Bs[row * LDW + (cg >> 1)]     = pk2bf(vb.x, vb.y);
            Bs[row * LDW + (cg >> 1) + 1] = pk2bf(vb.z, vb.w);
        }
        __syncthreads();
        short8 a[4], b[4];
        #pragma unroll
        for (int i = 0; i < 4; ++i)
            a[i] = *(const short8*)&As[(wm + i * 16 + l16) * LDW + quad * 4];
        #pragma unroll
        for (int i = 0; i < 4; ++i)
            b[i] = *(const short8*)&Bs[(wn + i * 16 + l16) * LDW + quad * 4];
        #pragma unroll
        for (int mi = 0; mi < 4; ++mi)
            #pragma unroll
            for (int ni = 0; ni < 4; ++ni)
                acc[mi][ni] = __builtin_amdgcn_mfma_f32_16x16x32_bf16(
                    a[mi], b[ni], acc[mi][ni], 0, 0, 0);
    }
    #pragma unroll
    for (int mi = 0; mi < 4; ++mi) {
        #pragma unroll
        for (int r = 0; r < 4; ++r) {
            int lrow = wm + mi * 16 + quad * 4 + r;
            int t = tok_s[lrow];
            if (t >= 0) {
                float* orow = out + (size_t)t * NDIM + out0 + wn + l16;
                #pragma unroll
                for (int ni = 0; ni < 4; ++ni)
                    orow[ni * 16] = acc[mi][ni][r];
            }
        }
    }
}

extern "C" void kernel_launch(void* const* d_in, const int* in_sizes, int n_in,
                              void* d_out, int out_size, void* d_ws, size_t ws_size,
                              hipStream_t stream) {
    const float* inp  = (const float*)d_in[0];
    const int*   gate = (const int*)d_in[1];
    const float* wgt  = (const float*)d_in[2];
    float*       out  = (float*)d_out;
    char* w = (char*)d_ws;

    if (ws_size >= WS_REQ) {
        int* cnt  = (int*)(w + O_CNT);
        int* tg0  = (int*)(w + O_TG0);
        int* te   = (int*)(w + O_TE);
        int* tend = (int*)(w + O_TEND);
        int* pos  = (int*)(w + O_POS);
        int* tok  = (int*)(w + O_TOK);
        ushort_t* pA = (ushort_t*)(w + O_PA);
        ushort_t* pW = (ushort_t*)(w + O_W);

        zero_k<<<1, 64, 0, stream>>>(cnt);
        hist_k<<<BATCH / 256, 256, 0, stream>>>(gate, cnt, pos);
        prep_k<<<BATCH / 4 + 2048 + 1, 256, 0, stream>>>(inp, wgt, gate, pos, cnt,
                                                         pA, pW, tok, tg0, te, tend);
        dim3 grid(NDIM / TN, MAXT, 1);
        moe_gemm4_k<<<grid, 256, 0, stream>>>(pA, pW, tg0, te, tend, tok, out);
    } else {
        int* cnt = (int*)d_ws;
        int* idx = cnt + NE;
        zero_k<<<1, 64, 0, stream>>>(cnt);
        bin_tokens_k<<<BATCH / 256, 256, 0, stream>>>(gate, cnt, idx);
        dim3 grid(NDIM / 128, BATCH / TM, NE);
        moe_gemm_k<<<grid, 256, 0, stream>>>(inp, wgt, cnt, idx, out);
    }
}

// Round 6
// 194.582 us; speedup vs baseline: 1.0067x; 1.0067x over previous
//
#include <hip/hip_runtime.h>
#include <hip/hip_bf16.h>

#define NE    16
#define KDIM  1024
#define NDIM  1024
#define BATCH 8192
#define TM    128
#define TN    64
#define MAXT  96          // max live m-tiles = 64 + 15 = 79, padded

typedef __attribute__((ext_vector_type(8))) short short8;
typedef __attribute__((ext_vector_type(4))) float floatx4;
typedef unsigned short ushort_t;

// ---- ws layout (bytes) ----
#define O_CNT  0
#define O_TG0  256
#define O_TE   1024
#define O_TEND 2048
#define O_POS  4096                     // int[8192]
#define O_TOK  36864                    // int[8320]
#define O_PA   73728                    // ushort[(8192+128)*1024]
#define O_W    17113088                 // ushort[16*1024*1024]
#define WS_REQ 50667520

#define GLOAD_LDS(gp, lp) __builtin_amdgcn_global_load_lds( \
    (const __attribute__((address_space(1))) unsigned int*)(gp), \
    (__attribute__((address_space(3))) unsigned int*)(lp), 16, 0, 0)

__device__ __forceinline__ unsigned int pk2bf(float x, float y) {
    __hip_bfloat162 h = __float22bfloat162_rn(make_float2(x, y));
    unsigned int u;
    __builtin_memcpy(&u, &h, 4);
    return u;
}

// ---------------- fast path ----------------

__global__ void zero_k(int* cnt) {
    if (threadIdx.x < NE) cnt[threadIdx.x] = 0;
}

__global__ void hist_k(const int* __restrict__ gate, int* cnt, int* pos) {
    int t = blockIdx.x * blockDim.x + threadIdx.x;
    if (t < BATCH) pos[t] = atomicAdd(&cnt[gate[t]], 1);
}

// persistent-style prep: 2048 uniform blocks, each does ONE token-gather item
// (4 rows) then ONE weight-cvt item (8192 floats); block 2048 builds tile map.
// Sequential phases keep live VGPRs ~50 -> 8 blocks/CU, one generation.
__global__ __launch_bounds__(256, 8) void prep_k(
        const float* __restrict__ inp, const float* __restrict__ wgt,
        const int* __restrict__ gate, const int* __restrict__ pos,
        const int* __restrict__ cnt, ushort_t* __restrict__ pA,
        ushort_t* __restrict__ pW, int* __restrict__ tok,
        int* __restrict__ tg0, int* __restrict__ te, int* __restrict__ tend) {
    __shared__ int ntot;
    const int b = blockIdx.x, tid = threadIdx.x;
    if (b < 2048) {
        // ---- phase 1: token gather (4 rows, 2 per pass over 256 threads) ----
        const int col = (tid & 127) * 8;
        const int half = tid >> 7;
        int g[2]; float4 v0[2], v1[2];
        #pragma unroll
        for (int p = 0; p < 2; ++p) {
            int t = b * 4 + p * 2 + half;
            int e = gate[t];
            int off = 0;
            #pragma unroll
            for (int k = 0; k < NE; ++k) off += (k < e) ? cnt[k] : 0;
            g[p] = off + pos[t];
            v0[p] = *(const float4*)&inp[(size_t)t * KDIM + col];
            v1[p] = *(const float4*)&inp[(size_t)t * KDIM + col + 4];
        }
        #pragma unroll
        for (int p = 0; p < 2; ++p) {
            uint4 u = make_uint4(pk2bf(v0[p].x, v0[p].y), pk2bf(v0[p].z, v0[p].w),
                                 pk2bf(v1[p].x, v1[p].y), pk2bf(v1[p].z, v1[p].w));
            *(uint4*)&pA[(size_t)g[p] * KDIM + col] = u;
            if (col == 0) tok[g[p]] = b * 4 + p * 2 + half;
        }
        // ---- phase 2: weight cvt (8192 floats, 8 float4 loads in flight) ----
        size_t base = (size_t)b * 8192 + tid * 8;
        float4 va[4], vb[4];
        #pragma unroll
        for (int i = 0; i < 4; ++i) {
            va[i] = *(const float4*)&wgt[base + i * 2048];
            vb[i] = *(const float4*)&wgt[base + i * 2048 + 4];
        }
        #pragma unroll
        for (int i = 0; i < 4; ++i) {
            uint4 u = make_uint4(pk2bf(va[i].x, va[i].y), pk2bf(va[i].z, va[i].w),
                                 pk2bf(vb[i].x, vb[i].y), pk2bf(vb[i].z, vb[i].w));
            *(uint4*)&pW[base + i * 2048] = u;
        }
    } else {
        if (tid < NE) {
            int o = 0, ts = 0;
            for (int j = 0; j < NE; ++j) {
                int c = cnt[j];
                if (j < tid) { o += c; ts += (c + TM - 1) / TM; }
            }
            int c = cnt[tid];
            if (tid == NE - 1) ntot = ts + (c + TM - 1) / TM;
            int nt = ts;
            for (int r = 0; r < c; r += TM) {
                int r0 = (r + TM <= c) ? r : (c > TM ? c - TM : 0);
                tg0[nt] = o + r0; te[nt] = tid; tend[nt] = o + c; ++nt;
            }
        }
        __syncthreads();
        for (int i = ntot + tid; i < MAXT; i += 256) {
            tg0[i] = 0; te[i] = 0; tend[i] = 0;
        }
    }
}

// single-buffer BK=64, m97-style 2-barrier, XOR-swizzled LDS chunks
__global__ __launch_bounds__(256, 5) void moe_gemm4_k(
        const ushort_t* __restrict__ pA, const ushort_t* __restrict__ pW,
        const int* __restrict__ tg0, const int* __restrict__ teArr,
        const int* __restrict__ tend, const int* __restrict__ tok,
        float* __restrict__ out) {
    const int y   = blockIdx.y;
    const int g0  = tg0[y];
    const int end = tend[y];
    if (g0 >= end) return;
    const int e    = teArr[y];
    const int out0 = blockIdx.x * TN;

    __shared__ ushort_t As[TM][64];   // 16 KB, chunk-swizzled
    __shared__ ushort_t Bs[TN][64];   //  8 KB
    __shared__ int tok_s[TM];

    const int tid = threadIdx.x;
    if (tid < TM) tok_s[tid] = tok[g0 + tid];

    const int wave = tid >> 6, lane = tid & 63;
    const int wm = (wave >> 1) * 64;
    const int wn = (wave & 1) * 32;
    const int quad = lane >> 4, l16 = lane & 15;

    const ushort_t* Ab = pA + (size_t)g0 * KDIM;
    const ushort_t* Bb = pW + (size_t)e * (KDIM * NDIM) + (size_t)out0 * KDIM;

    floatx4 acc[4][2] = {};
    const int slotw = wave * 64 + lane;

    for (int k0 = 0; k0 < KDIM; k0 += 64) {
        #pragma unroll
        for (int i = 0; i < 4; ++i) {
            int slot = i * 256 + slotw;
            int row = slot >> 3;
            int kc = (slot & 7) ^ (row & 7);
            GLOAD_LDS(Ab + (size_t)row * KDIM + k0 + kc * 8,
                      (ushort_t*)As + (size_t)(i * 256 + wave * 64) * 8);
        }
        #pragma unroll
        for (int i = 0; i < 2; ++i) {
            int slot = i * 256 + slotw;
            int row = slot >> 3;
            int kc = (slot & 7) ^ (row & 7);
            GLOAD_LDS(Bb + (size_t)row * KDIM + k0 + kc * 8,
                      (ushort_t*)Bs + (size_t)(i * 256 + wave * 64) * 8);
        }
        __syncthreads();                 // drain DMA -> LDS ready
        #pragma unroll
        for (int s = 0; s < 2; ++s) {
            short8 a[4], b[2];
            #pragma unroll
            for (int i = 0; i < 4; ++i) {
                int r = wm + i * 16 + l16;
                a[i] = *(const short8*)&As[r][((s * 4 + quad) ^ (r & 7)) * 8];
            }
            #pragma unroll
            for (int j = 0; j < 2; ++j) {
                int r = wn + j * 16 + l16;
                b[j] = *(const short8*)&Bs[r][((s * 4 + quad) ^ (r & 7)) * 8];
            }
            #pragma unroll
            for (int mi = 0; mi < 4; ++mi)
                #pragma unroll
                for (int nj = 0; nj < 2; ++nj)
                    acc[mi][nj] = __builtin_amdgcn_mfma_f32_16x16x32_bf16(
                        a[mi], b[nj], acc[mi][nj], 0, 0, 0);
        }
        __syncthreads();                 // protect LDS before next stage
    }

    // C/D layout: col=lane&15, row=quad*4+reg (verified m89/m91)
    #pragma unroll
    for (int mi = 0; mi < 4; ++mi) {
        #pragma unroll
        for (int r = 0; r < 4; ++r) {
            int lrow = wm + mi * 16 + quad * 4 + r;
            if (g0 + lrow < end) {
                int t = tok_s[lrow];
                float* orow = out + (size_t)t * NDIM + out0 + wn + l16;
                #pragma unroll
                for (int nj = 0; nj < 2; ++nj)
                    orow[nj * 16] = acc[mi][nj][r];
            }
        }
    }
}

// ---------------- fallback path (round-1, known-passing) ----------------
#define LDW 20
__global__ void bin_tokens_k(const int* __restrict__ gate, int* cnt, int* idx) {
    int t = blockIdx.x * blockDim.x + threadIdx.x;
    if (t < BATCH) {
        int e = gate[t];
        int p = atomicAdd(&cnt[e], 1);
        idx[e * BATCH + p] = t;
    }
}

__global__ __launch_bounds__(256) void moe_gemm_k(
        const float* __restrict__ inp, const float* __restrict__ wgt,
        const int* __restrict__ cnt, const int* __restrict__ idx,
        float* __restrict__ out) {
    const int e = blockIdx.z;
    const int n_e = cnt[e];
    const int row0 = blockIdx.y * TM;
    if (row0 >= n_e) return;
    const int out0 = blockIdx.x * 128;
    __shared__ unsigned int As[TM * LDW];
    __shared__ unsigned int Bs[TM * LDW];
    __shared__ int tok_s[TM];
    const int tid = threadIdx.x;
    if (tid < TM) {
        int g = row0 + tid;
        tok_s[tid] = (g < n_e) ? idx[e * BATCH + g] : -1;
    }
    const int wave = tid >> 6, lane = tid & 63;
    const int wm = (wave >> 1) * 64, wn = (wave & 1) * 64;
    const int quad = lane >> 4, l16 = lane & 15;
    floatx4 acc[4][4] = {};
    const int cg = (tid & 7) * 4;
    const int rbase = tid >> 3;
    const float* wbase = wgt + (size_t)e * KDIM * NDIM;
    for (int k0 = 0; k0 < KDIM; k0 += 32) {
        __syncthreads();
        #pragma unroll
        for (int p = 0; p < 4; ++p) {
            int row = p * 32 + rbase;
            int t = tok_s[row];
            float4 va = make_float4(0.f, 0.f, 0.f, 0.f);
            if (t >= 0) va = *(const float4*)&inp[(size_t)t * KDIM + k0 + cg];
            As[row * LDW + (cg >> 1)]     = pk2bf(va.x, va.y);
            As[row * LDW + (cg >> 1) + 1] = pk2bf(va.z, va.w);
            float4 vb = *(const float4*)&wbase[(size_t)(out0 + row) * KDIM + k0 + cg];
            Bs[row * LDW + (cg >> 1)]     = pk2bf(vb.x, vb.y);
            Bs[row * LDW + (cg >> 1) + 1] = pk2bf(vb.z, vb.w);
        }
        __syncthreads();
        short8 a[4], b[4];
        #pragma unroll
        for (int i = 0; i < 4; ++i)
            a[i] = *(const short8*)&As[(wm + i * 16 + l16) * LDW + quad * 4];
        #pragma unroll
        for (int i = 0; i < 4; ++i)
            b[i] = *(const short8*)&Bs[(wn + i * 16 + l16) * LDW + quad * 4];
        #pragma unroll
        for (int mi = 0; mi < 4; ++mi)
            #pragma unroll
            for (int ni = 0; ni < 4; ++ni)
                acc[mi][ni] = __builtin_amdgcn_mfma_f32_16x16x32_bf16(
                    a[mi], b[ni], acc[mi][ni], 0, 0, 0);
    }
    #pragma unroll
    for (int mi = 0; mi < 4; ++mi) {
        #pragma unroll
        for (int r = 0; r < 4; ++r) {
            int lrow = wm + mi * 16 + quad * 4 + r;
            int t = tok_s[lrow];
            if (t >= 0) {
                float* orow = out + (size_t)t * NDIM + out0 + wn + l16;
                #pragma unroll
                for (int ni = 0; ni < 4; ++ni)
                    orow[ni * 16] = acc[mi][ni][r];
            }
        }
    }
}

extern "C" void kernel_launch(void* const* d_in, const int* in_sizes, int n_in,
                              void* d_out, int out_size, void* d_ws, size_t ws_size,
                              hipStream_t stream) {
    const float* inp  = (const float*)d_in[0];
    const int*   gate = (const int*)d_in[1];
    const float* wgt  = (const float*)d_in[2];
    float*       out  = (float*)d_out;
    char* w = (char*)d_ws;

    if (ws_size >= WS_REQ) {
        int* cnt  = (int*)(w + O_CNT);
        int* tg0  = (int*)(w + O_TG0);
        int* te   = (int*)(w + O_TE);
        int* tend = (int*)(w + O_TEND);
        int* pos  = (int*)(w + O_POS);
        int* tok  = (int*)(w + O_TOK);
        ushort_t* pA = (ushort_t*)(w + O_PA);
        ushort_t* pW = (ushort_t*)(w + O_W);

        zero_k<<<1, 64, 0, stream>>>(cnt);
        hist_k<<<BATCH / 256, 256, 0, stream>>>(gate, cnt, pos);
        prep_k<<<2048 + 1, 256, 0, stream>>>(inp, wgt, gate, pos, cnt,
                                             pA, pW, tok, tg0, te, tend);
        dim3 grid(NDIM / TN, MAXT, 1);
        moe_gemm4_k<<<grid, 256, 0, stream>>>(pA, pW, tg0, te, tend, tok, out);
    } else {
        int* cnt = (int*)d_ws;
        int* idx = cnt + NE;
        zero_k<<<1, 64, 0, stream>>>(cnt);
        bin_tokens_k<<<BATCH / 256, 256, 0, stream>>>(gate, cnt, idx);
        dim3 grid(NDIM / 128, BATCH / TM, NE);
        moe_gemm_k<<<grid, 256, 0, stream>>>(inp, wgt, cnt, idx, out);
    }
}

// Round 7
// 192.761 us; speedup vs baseline: 1.0162x; 1.0094x over previous
//
#include <hip/hip_runtime.h>
#include <hip/hip_bf16.h>

#define NE    16
#define KDIM  1024
#define NDIM  1024
#define BATCH 8192
#define TM    128
#define TN    64
#define MAXT  96          // max live m-tiles = 64 + 15 = 79, padded

typedef __attribute__((ext_vector_type(8))) short short8;
typedef __attribute__((ext_vector_type(4))) float floatx4;
typedef unsigned short ushort_t;

// ---- ws layout (bytes) ----
#define O_CNT  0
#define O_TG0  256
#define O_TE   1024
#define O_TEND 2048
#define O_POS  4096                     // int[8192]
#define O_TOK  36864                    // int[8320]
#define O_PA   73728                    // ushort[(8192+128)*1024]
#define WS_REQ 17113088

#define GLOAD_LDS(gp, lp) __builtin_amdgcn_global_load_lds( \
    (const __attribute__((address_space(1))) unsigned int*)(gp), \
    (__attribute__((address_space(3))) unsigned int*)(lp), 16, 0, 0)

__device__ __forceinline__ unsigned int pk2bf(float x, float y) {
    __hip_bfloat162 h = __float22bfloat162_rn(make_float2(x, y));
    unsigned int u;
    __builtin_memcpy(&u, &h, 4);
    return u;
}

// ---------------- fast path ----------------

__global__ void zero_k(int* cnt) {
    if (threadIdx.x < NE) cnt[threadIdx.x] = 0;
}

__global__ void hist_k(const int* __restrict__ gate, int* cnt, int* pos) {
    int t = blockIdx.x * blockDim.x + threadIdx.x;
    if (t < BATCH) pos[t] = atomicAdd(&cnt[gate[t]], 1);
}

// token gather only (weights are consumed fp32 by the GEMM now);
// block 2048 builds the tile map
__global__ __launch_bounds__(256, 8) void prep_k(
        const float* __restrict__ inp, const int* __restrict__ gate,
        const int* __restrict__ pos, const int* __restrict__ cnt,
        ushort_t* __restrict__ pA, int* __restrict__ tok,
        int* __restrict__ tg0, int* __restrict__ te, int* __restrict__ tend) {
    __shared__ int ntot;
    const int b = blockIdx.x, tid = threadIdx.x;
    if (b < 2048) {
        const int col = (tid & 127) * 8;
        const int half = tid >> 7;
        int g[2]; float4 v0[2], v1[2];
        #pragma unroll
        for (int p = 0; p < 2; ++p) {
            int t = b * 4 + p * 2 + half;
            int e = gate[t];
            int off = 0;
            #pragma unroll
            for (int k = 0; k < NE; ++k) off += (k < e) ? cnt[k] : 0;
            g[p] = off + pos[t];
            v0[p] = *(const float4*)&inp[(size_t)t * KDIM + col];
            v1[p] = *(const float4*)&inp[(size_t)t * KDIM + col + 4];
        }
        #pragma unroll
        for (int p = 0; p < 2; ++p) {
            uint4 u = make_uint4(pk2bf(v0[p].x, v0[p].y), pk2bf(v0[p].z, v0[p].w),
                                 pk2bf(v1[p].x, v1[p].y), pk2bf(v1[p].z, v1[p].w));
            *(uint4*)&pA[(size_t)g[p] * KDIM + col] = u;
            if (col == 0) tok[g[p]] = b * 4 + p * 2 + half;
        }
    } else {
        if (tid < NE) {
            int o = 0, ts = 0;
            for (int j = 0; j < NE; ++j) {
                int c = cnt[j];
                if (j < tid) { o += c; ts += (c + TM - 1) / TM; }
            }
            int c = cnt[tid];
            if (tid == NE - 1) ntot = ts + (c + TM - 1) / TM;
            int nt = ts;
            for (int r = 0; r < c; r += TM) {
                int r0 = (r + TM <= c) ? r : (c > TM ? c - TM : 0);
                tg0[nt] = o + r0; te[nt] = tid; tend[nt] = o + c; ++nt;
            }
        }
        __syncthreads();
        for (int i = ntot + tid; i < MAXT; i += 256) {
            tg0[i] = 0; te[i] = 0; tend[i] = 0;
        }
    }
}

// BK=64 single-buffer: A via global_load_lds (bf16 pA), B staged fp32->bf16
// through VGPRs (cvt during staging), XOR-swizzled LDS
__global__ __launch_bounds__(256, 5) void moe_gemm5_k(
        const ushort_t* __restrict__ pA, const float* __restrict__ wgt,
        const int* __restrict__ tg0, const int* __restrict__ teArr,
        const int* __restrict__ tend, const int* __restrict__ tok,
        float* __restrict__ out) {
    const int y   = blockIdx.y;
    const int g0  = tg0[y];
    const int end = tend[y];
    if (g0 >= end) return;
    const int e    = teArr[y];
    const int out0 = blockIdx.x * TN;

    __shared__ ushort_t As[TM][64];   // 16 KB, chunk-swizzled
    __shared__ ushort_t Bs[TN][64];   //  8 KB
    __shared__ int tok_s[TM];

    const int tid = threadIdx.x;
    if (tid < TM) tok_s[tid] = tok[g0 + tid];

    const int wave = tid >> 6, lane = tid & 63;
    const int wm = (wave >> 1) * 64;
    const int wn = (wave & 1) * 32;
    const int quad = lane >> 4, l16 = lane & 15;

    const ushort_t* Ab = pA + (size_t)g0 * KDIM;
    const float*    Bw = wgt + ((size_t)e * NDIM + out0) * KDIM;

    floatx4 acc[4][2] = {};
    const int slotw = wave * 64 + lane;

    for (int k0 = 0; k0 < KDIM; k0 += 64) {
        // B: fp32 global loads first (4 float4 in flight)
        float4 bv[2][2];
        #pragma unroll
        for (int i = 0; i < 2; ++i) {
            int slot = i * 256 + slotw;
            int row = slot >> 3;
            int kc = (slot & 7) ^ (row & 7);
            const float* src = Bw + (size_t)row * KDIM + k0 + kc * 8;
            bv[i][0] = *(const float4*)src;
            bv[i][1] = *(const float4*)(src + 4);
        }
        // A: DMA direct to LDS (issues while B loads are in flight)
        #pragma unroll
        for (int i = 0; i < 4; ++i) {
            int slot = i * 256 + slotw;
            int row = slot >> 3;
            int kc = (slot & 7) ^ (row & 7);
            GLOAD_LDS(Ab + (size_t)row * KDIM + k0 + kc * 8,
                      (ushort_t*)As + (size_t)(i * 256 + wave * 64) * 8);
        }
        // B: cvt + linear ds_write_b128 (conflict-free)
        #pragma unroll
        for (int i = 0; i < 2; ++i) {
            int slot = i * 256 + slotw;
            uint4 u = make_uint4(pk2bf(bv[i][0].x, bv[i][0].y),
                                 pk2bf(bv[i][0].z, bv[i][0].w),
                                 pk2bf(bv[i][1].x, bv[i][1].y),
                                 pk2bf(bv[i][1].z, bv[i][1].w));
            *(uint4*)((ushort_t*)Bs + (size_t)slot * 8) = u;
        }
        __syncthreads();                 // drains A-DMA (vmcnt) + B writes
        #pragma unroll
        for (int s = 0; s < 2; ++s) {
            short8 a[4], b[2];
            #pragma unroll
            for (int i = 0; i < 4; ++i) {
                int r = wm + i * 16 + l16;
                a[i] = *(const short8*)&As[r][((s * 4 + quad) ^ (r & 7)) * 8];
            }
            #pragma unroll
            for (int j = 0; j < 2; ++j) {
                int r = wn + j * 16 + l16;
                b[j] = *(const short8*)&Bs[r][((s * 4 + quad) ^ (r & 7)) * 8];
            }
            #pragma unroll
            for (int mi = 0; mi < 4; ++mi)
                #pragma unroll
                for (int nj = 0; nj < 2; ++nj)
                    acc[mi][nj] = __builtin_amdgcn_mfma_f32_16x16x32_bf16(
                        a[mi], b[nj], acc[mi][nj], 0, 0, 0);
        }
        __syncthreads();                 // protect LDS before next stage
    }

    // C/D layout: col=lane&15, row=quad*4+reg (verified m89/m91)
    #pragma unroll
    for (int mi = 0; mi < 4; ++mi) {
        #pragma unroll
        for (int r = 0; r < 4; ++r) {
            int lrow = wm + mi * 16 + quad * 4 + r;
            if (g0 + lrow < end) {
                int t = tok_s[lrow];
                float* orow = out + (size_t)t * NDIM + out0 + wn + l16;
                #pragma unroll
                for (int nj = 0; nj < 2; ++nj)
                    orow[nj * 16] = acc[mi][nj][r];
            }
        }
    }
}

// ---------------- fallback path (round-1, known-passing) ----------------
#define LDW 20
__global__ void bin_tokens_k(const int* __restrict__ gate, int* cnt, int* idx) {
    int t = blockIdx.x * blockDim.x + threadIdx.x;
    if (t < BATCH) {
        int e = gate[t];
        int p = atomicAdd(&cnt[e], 1);
        idx[e * BATCH + p] = t;
    }
}

__global__ __launch_bounds__(256) void moe_gemm_k(
        const float* __restrict__ inp, const float* __restrict__ wgt,
        const int* __restrict__ cnt, const int* __restrict__ idx,
        float* __restrict__ out) {
    const int e = blockIdx.z;
    const int n_e = cnt[e];
    const int row0 = blockIdx.y * TM;
    if (row0 >= n_e) return;
    const int out0 = blockIdx.x * 128;
    __shared__ unsigned int As[TM * LDW];
    __shared__ unsigned int Bs[TM * LDW];
    __shared__ int tok_s[TM];
    const int tid = threadIdx.x;
    if (tid < TM) {
        int g = row0 + tid;
        tok_s[tid] = (g < n_e) ? idx[e * BATCH + g] : -1;
    }
    const int wave = tid >> 6, lane = tid & 63;
    const int wm = (wave >> 1) * 64, wn = (wave & 1) * 64;
    const int quad = lane >> 4, l16 = lane & 15;
    floatx4 acc[4][4] = {};
    const int cg = (tid & 7) * 4;
    const int rbase = tid >> 3;
    const float* wbase = wgt + (size_t)e * KDIM * NDIM;
    for (int k0 = 0; k0 < KDIM; k0 += 32) {
        __syncthreads();
        #pragma unroll
        for (int p = 0; p < 4; ++p) {
            int row = p * 32 + rbase;
            int t = tok_s[row];
            float4 va = make_float4(0.f, 0.f, 0.f, 0.f);
            if (t >= 0) va = *(const float4*)&inp[(size_t)t * KDIM + k0 + cg];
            As[row * LDW + (cg >> 1)]     = pk2bf(va.x, va.y);
            As[row * LDW + (cg >> 1) + 1] = pk2bf(va.z, va.w);
            float4 vb = *(const float4*)&wbase[(size_t)(out0 + row) * KDIM + k0 + cg];
            Bs[row * LDW + (cg >> 1)]     = pk2bf(vb.x, vb.y);
            Bs[row * LDW + (cg >> 1) + 1] = pk2bf(vb.z, vb.w);
        }
        __syncthreads();
        short8 a[4], b[4];
        #pragma unroll
        for (int i = 0; i < 4; ++i)
            a[i] = *(const short8*)&As[(wm + i * 16 + l16) * LDW + quad * 4];
        #pragma unroll
        for (int i = 0; i < 4; ++i)
            b[i] = *(const short8*)&Bs[(wn + i * 16 + l16) * LDW + quad * 4];
        #pragma unroll
        for (int mi = 0; mi < 4; ++mi)
            #pragma unroll
            for (int ni = 0; ni < 4; ++ni)
                acc[mi][ni] = __builtin_amdgcn_mfma_f32_16x16x32_bf16(
                    a[mi], b[ni], acc[mi][ni], 0, 0, 0);
    }
    #pragma unroll
    for (int mi = 0; mi < 4; ++mi) {
        #pragma unroll
        for (int r = 0; r < 4; ++r) {
            int lrow = wm + mi * 16 + quad * 4 + r;
            int t = tok_s[lrow];
            if (t >= 0) {
                float* orow = out + (size_t)t * NDIM + out0 + wn + l16;
                #pragma unroll
                for (int ni = 0; ni < 4; ++ni)
                    orow[ni * 16] = acc[mi][ni][r];
            }
        }
    }
}

extern "C" void kernel_launch(void* const* d_in, const int* in_sizes, int n_in,
                              void* d_out, int out_size, void* d_ws, size_t ws_size,
                              hipStream_t stream) {
    const float* inp  = (const float*)d_in[0];
    const int*   gate = (const int*)d_in[1];
    const float* wgt  = (const float*)d_in[2];
    float*       out  = (float*)d_out;
    char* w = (char*)d_ws;

    if (ws_size >= WS_REQ) {
        int* cnt  = (int*)(w + O_CNT);
        int* tg0  = (int*)(w + O_TG0);
        int* te   = (int*)(w + O_TE);
        int* tend = (int*)(w + O_TEND);
        int* pos  = (int*)(w + O_POS);
        int* tok  = (int*)(w + O_TOK);
        ushort_t* pA = (ushort_t*)(w + O_PA);

        zero_k<<<1, 64, 0, stream>>>(cnt);
        hist_k<<<BATCH / 256, 256, 0, stream>>>(gate, cnt, pos);
        prep_k<<<2048 + 1, 256, 0, stream>>>(inp, gate, pos, cnt,
                                             pA, tok, tg0, te, tend);
        dim3 grid(NDIM / TN, MAXT, 1);
        moe_gemm5_k<<<grid, 256, 0, stream>>>(pA, wgt, tg0, te, tend, tok, out);
    } else {
        int* cnt = (int*)d_ws;
        int* idx = cnt + NE;
        zero_k<<<1, 64, 0, stream>>>(cnt);
        bin_tokens_k<<<BATCH / 256, 256, 0, stream>>>(gate, cnt, idx);
        dim3 grid(NDIM / 128, BATCH / TM, NE);
        moe_gemm_k<<<grid, 256, 0, stream>>>(inp, wgt, cnt, idx, out);
    }
}